// Round 10
// baseline (441.560 us; speedup 1.0000x reference)
//
#include <hip/hip_runtime.h>

#define N_NODES 50000
#define E_EDGES 262144
#define P_ROWS 50048  // 782*64, padded

typedef __attribute__((ext_vector_type(8))) _Float16 f16x8;
typedef __attribute__((ext_vector_type(2))) _Float16 f16x2;
typedef __attribute__((ext_vector_type(4))) float f32x4;

union V16 { uint4 u; f16x8 h; };
union U32 { unsigned u; f16x2 p; };

// pack two f32 -> two f16 (RNE), a in low half
__device__ __forceinline__ unsigned h2pack(float a, float b) {
  union { _Float16 h[2]; unsigned u; } r;
  r.h[0] = (_Float16)a;
  r.h[1] = (_Float16)b;
  return r.u;
}
__device__ __forceinline__ void async_gather16(const void* gptr, void* lptr) {
  __builtin_amdgcn_global_load_lds(
      (const __attribute__((address_space(1))) void*)gptr,
      (__attribute__((address_space(3))) void*)lptr, 16, 0, 0);
}

// ---- prep: node_repr fp32 -> fp16 (RNE) ----
__global__ void cvt_node_kernel(const float* __restrict__ x, unsigned short* __restrict__ y) {
  int i = (blockIdx.x * 256 + threadIdx.x) * 8;
  float4 f0 = *(const float4*)(x + i);
  float4 f1 = *(const float4*)(x + i + 4);
  uint4 o;
  o.x = h2pack(f0.x, f0.y);
  o.y = h2pack(f0.z, f0.w);
  o.z = h2pack(f1.x, f1.y);
  o.w = h2pack(f1.z, f1.w);
  *(uint4*)(y + i) = o;
}

// ---- prep: W1 (1024x512 row-major in->out) -> W1pp2 fp16, 16-B units laid out
// [step(8)][sq=s*4+quad(16)][col(512)], unit = W1[k0..k0+8)[col], k0=s*256+step*32+quad*8
__global__ void prep_w1pp2_kernel(const float* __restrict__ w1, unsigned short* __restrict__ w1pp2) {
  int t = blockIdx.x * 256 + threadIdx.x;  // 65536 units
  int step = t >> 13;
  int rem = t & 8191;
  int sq = rem >> 9;
  int col = rem & 511;
  int s = sq >> 2, qd = sq & 3;
  int k0 = s * 256 + step * 32 + qd * 8;
  float f[8];
#pragma unroll
  for (int i = 0; i < 8; ++i) f[i] = w1[(size_t)(k0 + i) * 512 + col];
  uint4 o;
  o.x = h2pack(f[0], f[1]);
  o.y = h2pack(f[2], f[3]);
  o.z = h2pack(f[4], f[5]);
  o.w = h2pack(f[6], f[7]);
  *(uint4*)(w1pp2 + (size_t)t * 8) = o;
}

// ---- prep: out[e][c] = b2[c] ----
__global__ void init_out_kernel(float* __restrict__ out, const float* __restrict__ b2) {
  int i = blockIdx.x * 256 + threadIdx.x;
  float2 v; v.x = b2[0]; v.y = b2[1];
  *(float2*)(out + (size_t)i * 2) = v;
}

// ---- NEW (R10): node-level GEMM  P_t[n][c] = sum_k node[n][k] * W1[t*256+k][c]
//      t=0 -> Pa (W1a, applied to src side), t=1 -> Pb (W1b, dst side).
//      13 GFLOP total — reuses the PROVEN fragment formulas of the edge kernel
//      (identical A staging/ read, identical B read with s=t). ----
__global__ __launch_bounds__(256) void node_pab_kernel(
    const unsigned short* __restrict__ nodeb,  // [50000][256] f16
    const unsigned short* __restrict__ w1pp2,
    unsigned short* __restrict__ Pab) {        // [2][P_ROWS][512] f16
  __shared__ char smem[32768];
  const int tid = threadIdx.x;
  const int wid = tid >> 6;      // 0..3
  const int lane = tid & 63;
  const int quad = lane >> 4;
  const int l16 = lane & 15;
  const int bx = blockIdx.x;     // 0..3127
  const int table = bx & 1;
  const int half = (bx >> 1) & 1;
  const int ntile = bx >> 2;     // 0..781
  const int nrow0 = ntile * 64;
  const int cb = half * 256 + wid * 64;

  const char* nodeB = (const char*)nodeb;
  const char* w1B = (const char*)w1pp2;

  const unsigned bQ = (unsigned)((table * 4 + quad) * 8192 + (cb + l16) * 16);
  const unsigned aXor = (unsigned)(l16 & 7);
  const unsigned aBase = (unsigned)(l16 * 512);

  f32x4 acc[4][4];
#pragma unroll
  for (int mt = 0; mt < 4; ++mt)
#pragma unroll
    for (int nt = 0; nt < 4; ++nt)
      acc[mt][nt] = (f32x4){0.f, 0.f, 0.f, 0.f};

  // stage 64 node rows (consecutive ids, clamped; same slot/XOR scheme as edge A)
  {
    const int eh = tid >> 5;                                        // 0..7
    const unsigned wsw = (unsigned)(((tid & 31) ^ (eh & 7)) << 4);  // e&7 == eh&7
#pragma unroll
    for (int c = 0; c < 8; ++c) {
      int e = c * 8 + eh;
      int n = nrow0 + e;
      if (n > N_NODES - 1) n = N_NODES - 1;  // pad rows: value irrelevant, never gathered
      unsigned so = ((unsigned)n << 9) + wsw;
      async_gather16(nodeB + so, smem + c * 4096 + wid * 1024);
    }
  }
  __syncthreads();

  const char* w1s = w1B;
#pragma unroll 2
  for (int step = 0; step < 8; ++step) {
    V16 bf[4];
#pragma unroll
    for (int nt = 0; nt < 4; ++nt)
      bf[nt].u = *(const uint4*)(w1s + (bQ + (unsigned)(nt * 256)));
    const unsigned stq = (unsigned)(step * 4 + quad);
    V16 hi[4];
#pragma unroll
    for (int mt = 0; mt < 4; ++mt) {
      unsigned ao = (unsigned)(mt * 16 * 512) + aBase + ((stq ^ aXor) << 4);
      hi[mt].u = *(const uint4*)(smem + ao);
    }
#pragma unroll
    for (int mt = 0; mt < 4; ++mt)
#pragma unroll
      for (int nt = 0; nt < 4; ++nt)
        acc[mt][nt] = __builtin_amdgcn_mfma_f32_16x16x32_f16(hi[mt].h, bf[nt].h, acc[mt][nt], 0, 0, 0);
    w1s += 131072;
  }

  unsigned short* Pt = Pab + (size_t)table * ((size_t)P_ROWS * 512);
#pragma unroll
  for (int mt = 0; mt < 4; ++mt)
#pragma unroll
    for (int nt = 0; nt < 4; ++nt)
#pragma unroll
      for (int r = 0; r < 4; ++r) {
        int prow = nrow0 + mt * 16 + quad * 4 + r;  // C/D: row = quad*4 + r
        int pc = cb + nt * 16 + l16;
        _Float16 v = (_Float16)acc[mt][nt][r];
        Pt[(size_t)prow * 512 + pc] = *(unsigned short*)&v;
      }
}

// ---- main fused kernel R10: FACTORIZED. block = 64 edges x 512 cols (8 waves),
//      wave = 64e x 64c. K-loop runs ONLY s=2 (|hi-hj|) and s=3 (hi*hj): 32 MFMA
//      + 8 B-loads per step (both halved vs R9). Pa[src]+Pb[dst] added in epilogue
//      (f16 gathers from L3-resident 102MB tables). WHY: R9 proved the old shape's
//      MFMA demand (~20K cyc/CU-round) and W1 L2-stream (~19K cyc) are co-critical
//      and occupancy is HW-pinned at 2 waves/SIMD (68 VGPR + 64 acc AGPR = 132 >
//      128 boundary; compiler won't go lower). Factorization halves BOTH demands,
//      and bf 64->32 regs may drop total <=128 -> 4 waves/SIMD as a bonus. ----
__global__ __launch_bounds__(512) void edge_mlp_kernel(
    const unsigned short* __restrict__ nodeb,  // [50000][256] fp16
    const unsigned short* __restrict__ w1pp2,  // repacked W1 (see prep)
    const unsigned short* __restrict__ Pab,    // [2][P_ROWS][512] f16
    const int* __restrict__ src,
    const int* __restrict__ dst,
    const float* __restrict__ b1,
    const float* __restrict__ w2,   // [512][2] fp32
    float* __restrict__ out) {      // [E][2] fp32, pre-init with b2
  // hi: [0,32K) — 64 edges x 512 B; hj: [32K,64K)
  // 16-B unit slot for (e, st, q): e*32 + ((st*4+q) ^ (e&7))
  __shared__ char smem[65536];

  const int tid = threadIdx.x;
  const int wid = tid >> 6;      // 0..7 -> 8 waves x 64 cols = all 512 cols
  const int lane = tid & 63;
  const int quad = lane >> 4;
  const int l16 = lane & 15;
  const int bx = blockIdx.x;     // 0..4095
  // XCD swizzle: xc = bx&7; neighbor m-tiles share an XCD
  const int xc = bx & 7;
  const int m_idx = (bx >> 3) * 8 + xc;      // 0..4095 (64-edge tiles)
  const int row0 = m_idx * 64;
  const int n0 = wid * 64;

  const char* nodeB = (const char*)nodeb;
  const char* w1B = (const char*)w1pp2;

  // ---- B load base: byte(s2,nt,step) = bQ + (s2+2)*32768 + nt*256 + step*131072 ----
  const unsigned bQ = (unsigned)(quad * 8192 + (n0 + l16) * 16);
  const char* w1s = w1B;

  // ---- A reader base: byte = (mt*16+l16)*512 + (((st*4+q)^(l16&7))<<4) ----
  const unsigned aXor = (unsigned)(l16 & 7);
  const unsigned aBase = (unsigned)(l16 * 512);

  f32x4 acc[4][4];
#pragma unroll
  for (int mt = 0; mt < 4; ++mt)
#pragma unroll
    for (int nt = 0; nt < 4; ++nt)
      acc[mt][nt] = (f32x4){0.f, 0.f, 0.f, 0.f};

  // ---- prologue: stage ALL of A (hi+hj, 64 edges x 512 B each region) ----
  {
    const int eh = tid >> 5;                                        // 0..15
    const unsigned wsw = (unsigned)(((tid & 31) ^ (eh & 7)) << 4);
#pragma unroll
    for (int c = 0; c < 4; ++c) {
      int e = c * 16 + eh;
      unsigned so = ((unsigned)src[row0 + e] << 9) + wsw;
      unsigned do_ = ((unsigned)dst[row0 + e] << 9) + wsw;
      async_gather16(nodeB + so, smem + c * 8192 + wid * 1024);
      async_gather16(nodeB + do_, smem + 32768 + c * 8192 + wid * 1024);
    }
  }
  __syncthreads();  // the ONLY barrier

#pragma unroll 2
  for (int step = 0; step < 8; ++step) {
    // B(t) loads: only s=2 (a2) and s=3 (a3) slices survive the factorization
    V16 bf2[2][4];
#pragma unroll
    for (int s2 = 0; s2 < 2; ++s2)
#pragma unroll
      for (int nt = 0; nt < 4; ++nt)
        bf2[s2][nt].u = *(const uint4*)(w1s + (bQ + (unsigned)((s2 + 2) * 32768 + nt * 256)));
    // A fragments from LDS (read-only, no sync needed)
    const unsigned stq = (unsigned)(step * 4 + quad);
    V16 hi[4], hj[4];
#pragma unroll
    for (int mt = 0; mt < 4; ++mt) {
      unsigned ao = (unsigned)(mt * 16 * 512) + aBase + ((stq ^ aXor) << 4);
      hi[mt].u = *(const uint4*)(smem + ao);
      hj[mt].u = *(const uint4*)(smem + 32768 + ao);
    }
    // build a2=|hi-hj|, a3=hi*hj with packed fp16 (3 VALU/word), MFMA s=2,3
#pragma unroll
    for (int mt = 0; mt < 4; ++mt) {
      const unsigned hw[4] = {hi[mt].u.x, hi[mt].u.y, hi[mt].u.z, hi[mt].u.w};
      const unsigned jw[4] = {hj[mt].u.x, hj[mt].u.y, hj[mt].u.z, hj[mt].u.w};
      unsigned d[4], pr[4];
#pragma unroll
      for (int w = 0; w < 4; ++w) {
        U32 hx, jx, dd, pp;
        hx.u = hw[w];
        jx.u = jw[w];
        dd.p = hx.p - jx.p;            // v_pk_add_f16 (neg mod)
        d[w] = dd.u & 0x7fff7fffu;     // abs: clear sign bits (exact)
        pp.p = hx.p * jx.p;            // v_pk_mul_f16
        pr[w] = pp.u;
      }
      V16 a2, a3;
      a2.u = make_uint4(d[0], d[1], d[2], d[3]);
      a3.u = make_uint4(pr[0], pr[1], pr[2], pr[3]);
#pragma unroll
      for (int nt = 0; nt < 4; ++nt)
        acc[mt][nt] = __builtin_amdgcn_mfma_f32_16x16x32_f16(a2.h, bf2[0][nt].h, acc[mt][nt], 0, 0, 0);
#pragma unroll
      for (int nt = 0; nt < 4; ++nt)
        acc[mt][nt] = __builtin_amdgcn_mfma_f32_16x16x32_f16(a3.h, bf2[1][nt].h, acc[mt][nt], 0, 0, 0);
    }
    w1s += 131072;
  }

  // ---- epilogue: + Pa[src]+Pb[dst], bias + ReLU + W2, shuffle reduce, atomic out ----
  const unsigned short* Pa = Pab;
  const unsigned short* Pb = Pab + (size_t)P_ROWS * 512;
#pragma unroll
  for (int mt = 0; mt < 4; ++mt) {
    int si[4], di[4];
#pragma unroll
    for (int r = 0; r < 4; ++r) {
      int e = row0 + mt * 16 + quad * 4 + r;
      si[r] = src[e];
      di[r] = dst[e];
    }
    float pc0[4] = {0.f, 0.f, 0.f, 0.f};
    float pc1[4] = {0.f, 0.f, 0.f, 0.f};
#pragma unroll
    for (int nt = 0; nt < 4; ++nt) {
      int gc = n0 + nt * 16 + l16;
      float b1v = b1[gc];
      float w20 = w2[gc * 2 + 0];
      float w21 = w2[gc * 2 + 1];
#pragma unroll
      for (int r = 0; r < 4; ++r) {
        float pa = (float)*(const _Float16*)(Pa + (size_t)si[r] * 512 + gc);
        float pb = (float)*(const _Float16*)(Pb + (size_t)di[r] * 512 + gc);
        float v = fmaxf(acc[mt][nt][r] + pa + pb + b1v, 0.f);
        pc0[r] = fmaf(v, w20, pc0[r]);
        pc1[r] = fmaf(v, w21, pc1[r]);
      }
    }
#pragma unroll
    for (int r = 0; r < 4; ++r) {
      float s0 = pc0[r], s1 = pc1[r];
#pragma unroll
      for (int off = 1; off < 16; off <<= 1) {
        s0 += __shfl_xor(s0, off);
        s1 += __shfl_xor(s1, off);
      }
      int e = row0 + mt * 16 + quad * 4 + r;  // C/D: row = quad*4 + r
      if (l16 == 0) unsafeAtomicAdd(&out[(size_t)e * 2 + 0], s0);
      if (l16 == 1) unsafeAtomicAdd(&out[(size_t)e * 2 + 1], s1);
    }
  }
}

extern "C" void kernel_launch(void* const* d_in, const int* in_sizes, int n_in,
                              void* d_out, int out_size, void* d_ws, size_t ws_size,
                              hipStream_t stream) {
  const float* node = (const float*)d_in[0];
  const int* src = (const int*)d_in[1];
  const int* dst = (const int*)d_in[2];
  const float* W1 = (const float*)d_in[3];
  const float* b1 = (const float*)d_in[4];
  const float* W2 = (const float*)d_in[5];
  const float* b2 = (const float*)d_in[6];
  float* out = (float*)d_out;

  // workspace layout (129,146,880 B total):
  unsigned short* nodeb = (unsigned short*)d_ws;                      // 25,600,000 B
  unsigned short* w1pp2 = (unsigned short*)((char*)d_ws + 25600000);  //  1,048,576 B
  unsigned short* Pab   = (unsigned short*)((char*)d_ws + 26648576);  // 2*50048*512*2 B

  cvt_node_kernel<<<6250, 256, 0, stream>>>(node, nodeb);
  prep_w1pp2_kernel<<<256, 256, 0, stream>>>(W1, w1pp2);
  node_pab_kernel<<<3128, 256, 0, stream>>>(nodeb, w1pp2, Pab);
  init_out_kernel<<<1024, 256, 0, stream>>>(out, b2);
  edge_mlp_kernel<<<4096, 512, 0, stream>>>(nodeb, w1pp2, Pab, src, dst, b1, W2, out);
}

// Round 11
// 411.213 us; speedup vs baseline: 1.0738x; 1.0738x over previous
//
#include <hip/hip_runtime.h>

#define N_NODES 50000
#define E_EDGES 262144

typedef __attribute__((ext_vector_type(8))) _Float16 f16x8;
typedef __attribute__((ext_vector_type(2))) _Float16 f16x2;
typedef __attribute__((ext_vector_type(4))) float f32x4;

union V16 { uint4 u; f16x8 h; };
union U32 { unsigned u; f16x2 p; };

// pack two f32 -> two f16 (RNE), a in low half
__device__ __forceinline__ unsigned h2pack(float a, float b) {
  union { _Float16 h[2]; unsigned u; } r;
  r.h[0] = (_Float16)a;
  r.h[1] = (_Float16)b;
  return r.u;
}
__device__ __forceinline__ void async_gather16(const void* gptr, void* lptr) {
  __builtin_amdgcn_global_load_lds(
      (const __attribute__((address_space(1))) void*)gptr,
      (__attribute__((address_space(3))) void*)lptr, 16, 0, 0);
}

// ---- fused prep (R11): blocks [0,6250) cvt node fp32->fp16; [6250,6506) repack W1.
//      One launch instead of two; both jobs are BW-bound and independent. ----
__global__ __launch_bounds__(256) void prep_all_kernel(
    const float* __restrict__ node, const float* __restrict__ w1,
    unsigned short* __restrict__ nodeb, unsigned short* __restrict__ w1pp2) {
  const int bx = blockIdx.x;
  if (bx < 6250) {
    // node_repr fp32 -> fp16 (RNE)
    int i = (bx * 256 + threadIdx.x) * 8;
    float4 f0 = *(const float4*)(node + i);
    float4 f1 = *(const float4*)(node + i + 4);
    uint4 o;
    o.x = h2pack(f0.x, f0.y);
    o.y = h2pack(f0.z, f0.w);
    o.z = h2pack(f1.x, f1.y);
    o.w = h2pack(f1.z, f1.w);
    *(uint4*)(nodeb + i) = o;
  } else {
    // W1 (1024x512 row-major in->out) -> fp16 16-B units laid out
    // [step(8)][sq=s*4+quad(16)][col(512)], unit = W1[k0..k0+8)[col],
    // k0 = s*256 + step*32 + quad*8
    int t = (bx - 6250) * 256 + threadIdx.x;  // 65536 units
    int step = t >> 13;
    int rem = t & 8191;
    int sq = rem >> 9;
    int col = rem & 511;
    int s = sq >> 2, qd = sq & 3;
    int k0 = s * 256 + step * 32 + qd * 8;
    float f[8];
#pragma unroll
    for (int i = 0; i < 8; ++i) f[i] = w1[(size_t)(k0 + i) * 512 + col];
    uint4 o;
    o.x = h2pack(f[0], f[1]);
    o.y = h2pack(f[2], f[3]);
    o.z = h2pack(f[4], f[5]);
    o.w = h2pack(f[6], f[7]);
    *(uint4*)(w1pp2 + (size_t)t * 8) = o;
  }
}

// ---- main fused kernel R11: the VERIFIED 339 µs body (R8/R9: 512 thr, 8 waves,
//      64 edges x 512 cols, wave = 64e x 64c, f16 datapath, one staging barrier,
//      K-loop byte-identical to R9). Factorization (R10) reverted: measured wash
//      (edge -20 µs, pab kernel +40-60, total regressed).
//      NEW in R11 (epilogue only):
//      * no atomics, no init_out kernel: the block's 8 waves are the sole writers
//        of its 64 edges -> LDS cross-wave reduction (4 KB, smem reused after the
//        K-loop) + ONE plain coalesced store of b2[c] + sum.
//      Occupancy note (measured R8/R9): arch 68 VGPR + 64 acc AGPR = 132 > 128
//      boundary -> HW-pinned 2 waves/SIMD; compiler won't go below 68, and every
//      forced cap (launch_bounds 2nd arg) spilled catastrophically. 811 TF eff
//      ~= 90% of the plain-HIP 2-barrier structure ceiling (~900 TF). ----
__global__ __launch_bounds__(512) void edge_mlp_kernel(
    const unsigned short* __restrict__ nodeb,  // [50000][256] fp16
    const unsigned short* __restrict__ w1pp2,  // repacked W1 (see prep)
    const int* __restrict__ src,
    const int* __restrict__ dst,
    const float* __restrict__ b1,
    const float* __restrict__ w2,   // [512][2] fp32
    const float* __restrict__ b2,   // [2] fp32
    float* __restrict__ out) {      // [E][2] fp32 (written once, no pre-init)
  // hi: [0,32K) — 64 edges x 512 B; hj: [32K,64K)
  // 16-B unit slot for (e, st, q): e*32 + ((st*4+q) ^ (e&7))
  __shared__ char smem[65536];

  const int tid = threadIdx.x;
  const int wid = tid >> 6;      // 0..7 -> 8 waves x 64 cols = all 512 cols
  const int lane = tid & 63;
  const int quad = lane >> 4;
  const int l16 = lane & 15;
  const int bx = blockIdx.x;     // 0..4095
  // XCD swizzle: xc = bx&7; neighbor m-tiles share an XCD
  const int xc = bx & 7;
  const int m_idx = (bx >> 3) * 8 + xc;      // 0..4095 (64-edge tiles)
  const int row0 = m_idx * 64;
  const int n0 = wid * 64;

  const char* nodeB = (const char*)nodeb;
  const char* w1B = (const char*)w1pp2;

  // ---- B load base: byte(s,nt,step) = bQ + s*32768 + nt*256 + step*131072 ----
  const unsigned bQ = (unsigned)(quad * 8192 + (n0 + l16) * 16);
  const char* w1s = w1B;

  // ---- A reader base: byte = (mt*16+l16)*512 + (((st*4+q)^(l16&7))<<4) ----
  const unsigned aXor = (unsigned)(l16 & 7);
  const unsigned aBase = (unsigned)(l16 * 512);

  f32x4 acc[4][4];
#pragma unroll
  for (int mt = 0; mt < 4; ++mt)
#pragma unroll
    for (int nt = 0; nt < 4; ++nt)
      acc[mt][nt] = (f32x4){0.f, 0.f, 0.f, 0.f};

  // ---- prologue: stage ALL of A (hi+hj, 64 edges x 512 B each region) ----
  // call c stages slots v = c*512+tid; e = v>>5 = c*16 + (tid>>5); w = tid&31
  // dst byte = v*16 (linear); source carries the XOR swizzle u = w ^ (e&7).
  {
    const int eh = tid >> 5;                                        // 0..15
    const unsigned wsw = (unsigned)(((tid & 31) ^ (eh & 7)) << 4);
#pragma unroll
    for (int c = 0; c < 4; ++c) {
      int e = c * 16 + eh;
      unsigned so = ((unsigned)src[row0 + e] << 9) + wsw;
      unsigned do_ = ((unsigned)dst[row0 + e] << 9) + wsw;
      async_gather16(nodeB + so, smem + c * 8192 + wid * 1024);
      async_gather16(nodeB + do_, smem + 32768 + c * 8192 + wid * 1024);
    }
  }
  __syncthreads();  // staging barrier

#pragma unroll 2
  for (int step = 0; step < 8; ++step) {
    // B(t) loads — compiler emits fine-grained vmcnt
    V16 bf[4][4];
#pragma unroll
    for (int s = 0; s < 4; ++s)
#pragma unroll
      for (int nt = 0; nt < 4; ++nt)
        bf[s][nt].u = *(const uint4*)(w1s + (bQ + (unsigned)(s * 32768 + nt * 256)));
    // A fragments from LDS (read-only, no sync needed)
    const unsigned stq = (unsigned)(step * 4 + quad);
    V16 hi[4], hj[4];
#pragma unroll
    for (int mt = 0; mt < 4; ++mt) {
      unsigned ao = (unsigned)(mt * 16 * 512) + aBase + ((stq ^ aXor) << 4);
      hi[mt].u = *(const uint4*)(smem + ao);
      hj[mt].u = *(const uint4*)(smem + 32768 + ao);
    }
    // MFMA s=0 (hi), s=1 (hj)
#pragma unroll
    for (int mt = 0; mt < 4; ++mt)
#pragma unroll
      for (int nt = 0; nt < 4; ++nt)
        acc[mt][nt] = __builtin_amdgcn_mfma_f32_16x16x32_f16(hi[mt].h, bf[0][nt].h, acc[mt][nt], 0, 0, 0);
#pragma unroll
    for (int mt = 0; mt < 4; ++mt)
#pragma unroll
      for (int nt = 0; nt < 4; ++nt)
        acc[mt][nt] = __builtin_amdgcn_mfma_f32_16x16x32_f16(hj[mt].h, bf[1][nt].h, acc[mt][nt], 0, 0, 0);
    // build a2=|hi-hj|, a3=hi*hj with packed fp16 (3 VALU/word), MFMA s=2,3
#pragma unroll
    for (int mt = 0; mt < 4; ++mt) {
      const unsigned hw[4] = {hi[mt].u.x, hi[mt].u.y, hi[mt].u.z, hi[mt].u.w};
      const unsigned jw[4] = {hj[mt].u.x, hj[mt].u.y, hj[mt].u.z, hj[mt].u.w};
      unsigned d[4], pr[4];
#pragma unroll
      for (int w = 0; w < 4; ++w) {
        U32 hx, jx, dd, pp;
        hx.u = hw[w];
        jx.u = jw[w];
        dd.p = hx.p - jx.p;            // v_pk_add_f16 (neg mod)
        d[w] = dd.u & 0x7fff7fffu;     // abs: clear sign bits (exact)
        pp.p = hx.p * jx.p;            // v_pk_mul_f16
        pr[w] = pp.u;
      }
      V16 a2, a3;
      a2.u = make_uint4(d[0], d[1], d[2], d[3]);
      a3.u = make_uint4(pr[0], pr[1], pr[2], pr[3]);
#pragma unroll
      for (int nt = 0; nt < 4; ++nt)
        acc[mt][nt] = __builtin_amdgcn_mfma_f32_16x16x32_f16(a2.h, bf[2][nt].h, acc[mt][nt], 0, 0, 0);
#pragma unroll
      for (int nt = 0; nt < 4; ++nt)
        acc[mt][nt] = __builtin_amdgcn_mfma_f32_16x16x32_f16(a3.h, bf[3][nt].h, acc[mt][nt], 0, 0, 0);
    }
    w1s += 131072;
  }

  // ---- epilogue v2: bias + ReLU + W2, 16-lane shuffle reduce, then LDS
  //      cross-wave reduction (smem reused) + ONE plain store per out element ----
  float* red = (float*)smem;   // [8 waves][64 edges][2] f32 = 4 KB
  __syncthreads();             // all waves done reading A tiles from LDS
#pragma unroll
  for (int mt = 0; mt < 4; ++mt) {
    float pc0[4] = {0.f, 0.f, 0.f, 0.f};
    float pc1[4] = {0.f, 0.f, 0.f, 0.f};
#pragma unroll
    for (int nt = 0; nt < 4; ++nt) {
      int gc = n0 + nt * 16 + l16;
      float b1v = b1[gc];
      float w20 = w2[gc * 2 + 0];
      float w21 = w2[gc * 2 + 1];
#pragma unroll
      for (int r = 0; r < 4; ++r) {
        float v = fmaxf(acc[mt][nt][r] + b1v, 0.f);
        pc0[r] = fmaf(v, w20, pc0[r]);
        pc1[r] = fmaf(v, w21, pc1[r]);
      }
    }
#pragma unroll
    for (int r = 0; r < 4; ++r) {
      float s0 = pc0[r], s1 = pc1[r];
#pragma unroll
      for (int off = 1; off < 16; off <<= 1) {
        s0 += __shfl_xor(s0, off);
        s1 += __shfl_xor(s1, off);
      }
      int el = mt * 16 + quad * 4 + r;  // C/D: row = quad*4 + r
      if (l16 == 0) red[wid * 128 + el * 2 + 0] = s0;
      if (l16 == 1) red[wid * 128 + el * 2 + 1] = s1;
    }
  }
  __syncthreads();
  if (tid < 128) {
    // tid = el*2 + c
    float s = b2[tid & 1];
#pragma unroll
    for (int w = 0; w < 8; ++w) s += red[w * 128 + tid];
    out[(size_t)row0 * 2 + tid] = s;
  }
}

extern "C" void kernel_launch(void* const* d_in, const int* in_sizes, int n_in,
                              void* d_out, int out_size, void* d_ws, size_t ws_size,
                              hipStream_t stream) {
  const float* node = (const float*)d_in[0];
  const int* src = (const int*)d_in[1];
  const int* dst = (const int*)d_in[2];
  const float* W1 = (const float*)d_in[3];
  const float* b1 = (const float*)d_in[4];
  const float* W2 = (const float*)d_in[5];
  const float* b2 = (const float*)d_in[6];
  float* out = (float*)d_out;

  unsigned short* nodeb = (unsigned short*)d_ws;                      // 25,600,000 B
  unsigned short* w1pp2 = (unsigned short*)((char*)d_ws + 25600000);  // 1,048,576 B

  prep_all_kernel<<<6506, 256, 0, stream>>>(node, W1, nodeb, w1pp2);
  edge_mlp_kernel<<<4096, 512, 0, stream>>>(nodeb, w1pp2, src, dst, b1, W2, b2, out);
}

// Round 12
// 399.792 us; speedup vs baseline: 1.1045x; 1.0286x over previous
//
#include <hip/hip_runtime.h>

#define N_NODES 50000
#define E_EDGES 262144

typedef __attribute__((ext_vector_type(8))) _Float16 f16x8;
typedef __attribute__((ext_vector_type(2))) _Float16 f16x2;
typedef __attribute__((ext_vector_type(16))) float f32x16;

union V16 { uint4 u; f16x8 h; };
union U32 { unsigned u; f16x2 p; };

// pack two f32 -> two f16 (RNE), a in low half
__device__ __forceinline__ unsigned h2pack(float a, float b) {
  union { _Float16 h[2]; unsigned u; } r;
  r.h[0] = (_Float16)a;
  r.h[1] = (_Float16)b;
  return r.u;
}
__device__ __forceinline__ void async_gather16(const void* gptr, void* lptr) {
  __builtin_amdgcn_global_load_lds(
      (const __attribute__((address_space(1))) void*)gptr,
      (__attribute__((address_space(3))) void*)lptr, 16, 0, 0);
}

// ---- fused prep (unchanged from R11): blocks [0,6250) cvt node fp32->fp16;
//      [6250,6506) repack W1 into 16-B units [step(8)][sq(16)][col(512)],
//      unit = W1[k0..k0+8)[col], k0 = s*256 + step*32 + qd*8.
//      NOTE: this layout serves BOTH MFMA shapes — for 32x32x16 the qd index is
//      re-interpreted as slice*2 + khalf (same k0 arithmetic). ----
__global__ __launch_bounds__(256) void prep_all_kernel(
    const float* __restrict__ node, const float* __restrict__ w1,
    unsigned short* __restrict__ nodeb, unsigned short* __restrict__ w1pp2) {
  const int bx = blockIdx.x;
  if (bx < 6250) {
    int i = (bx * 256 + threadIdx.x) * 8;
    float4 f0 = *(const float4*)(node + i);
    float4 f1 = *(const float4*)(node + i + 4);
    uint4 o;
    o.x = h2pack(f0.x, f0.y);
    o.y = h2pack(f0.z, f0.w);
    o.z = h2pack(f1.x, f1.y);
    o.w = h2pack(f1.z, f1.w);
    *(uint4*)(nodeb + i) = o;
  } else {
    int t = (bx - 6250) * 256 + threadIdx.x;  // 65536 units
    int step = t >> 13;
    int rem = t & 8191;
    int sq = rem >> 9;
    int col = rem & 511;
    int s = sq >> 2, qd = sq & 3;
    int k0 = s * 256 + step * 32 + qd * 8;
    float f[8];
#pragma unroll
    for (int i = 0; i < 8; ++i) f[i] = w1[(size_t)(k0 + i) * 512 + col];
    uint4 o;
    o.x = h2pack(f[0], f[1]);
    o.y = h2pack(f[2], f[3]);
    o.z = h2pack(f[4], f[5]);
    o.w = h2pack(f[6], f[7]);
    *(uint4*)(w1pp2 + (size_t)t * 8) = o;
  }
}

// ---- main fused kernel R12: same macro-structure as the verified R11 (512 thr,
//      8 waves, 64 edges x 512 cols, wave = 64e x 64c, one staging barrier,
//      LDS cross-wave epilogue reduce, no atomics) but the K-loop now uses
//      v_mfma_f32_32x32x16_f16: 32 MFMAs/K-step/wave (was 64) at the 32x32 pipe
//      rate (2495 vs 2075 TF measured) -> ~17% less matrix-pipe time and half
//      the MFMA issue/dependency chain for the 2 resident waves/SIMD to hide.
//      Fragment mappings (m74/m101-verified): A/B: row|col = lane&31,
//      k = (lane>>5)*8 + e; C/D: col = lane&31, row = (reg&3)+8(reg>>2)+4(lane>>5).
//      A-LDS swizzle generalized: slot u' = u ^ (row&31) (stage source carries it).
//      Occupancy note (R8/R9 measured): 64 acc AGPR + ~70 arch = >128 total ->
//      HW-pinned 2 waves/SIMD; forcing lower VGPR spills catastrophically. ----
__global__ __launch_bounds__(512) void edge_mlp_kernel(
    const unsigned short* __restrict__ nodeb,  // [50000][256] fp16
    const unsigned short* __restrict__ w1pp2,  // repacked W1 (see prep)
    const int* __restrict__ src,
    const int* __restrict__ dst,
    const float* __restrict__ b1,
    const float* __restrict__ w2,   // [512][2] fp32
    const float* __restrict__ b2,   // [2] fp32
    float* __restrict__ out) {      // [E][2] fp32 (written once, no pre-init)
  // hi: [0,32K) — 64 edges x 512 B; hj: [32K,64K)
  // 16-B unit slot for (edge row, unit u): row*32 + (u ^ (row&31))
  __shared__ char smem[65536];

  const int tid = threadIdx.x;
  const int wid = tid >> 6;      // 0..7 -> 8 waves x 64 cols = all 512 cols
  const int lane = tid & 63;
  const int l32 = lane & 31;
  const int khalf = lane >> 5;   // k-half within a K16 slice
  const int bx = blockIdx.x;     // 0..4095
  // XCD swizzle: xc = bx&7; neighbor m-tiles share an XCD
  const int xc = bx & 7;
  const int m_idx = (bx >> 3) * 8 + xc;      // 0..4095 (64-edge tiles)
  const int row0 = m_idx * 64;
  const int n0 = wid * 64;

  const char* nodeB = (const char*)nodeb;
  const char* w1B = (const char*)w1pp2;

  // ---- B load: addr = w1s + bQ + s*32768 + slice*16384 + nt2*512 (+step*131072)
  //      (unit index sq = s*4 + slice*2 + khalf; col = n0 + nt2*32 + l32) ----
  const unsigned bQ = (unsigned)(khalf * 8192 + (n0 + l32) * 16);
  const char* w1s = w1B;

  // ---- A reader: row = mt2*32 + l32 (row&31 == l32); unit u = step*4+slice*2+khalf
  //      byte = row*512 + ((u ^ l32) << 4) ----
  const unsigned aXor = (unsigned)l32;
  const unsigned aBase = (unsigned)(l32 * 512);

  f32x16 acc[2][2];
#pragma unroll
  for (int mt2 = 0; mt2 < 2; ++mt2)
#pragma unroll
    for (int nt2 = 0; nt2 < 2; ++nt2)
#pragma unroll
      for (int r = 0; r < 16; ++r)
        acc[mt2][nt2][r] = 0.f;

  // ---- prologue: stage ALL of A (hi+hj, 64 edges x 512 B each region) ----
  // call c stages slots v = c*512+tid; e = v>>5 = c*16 + (tid>>5); w = tid&31.
  // LDS dest linear (base + lane*16); source carries XOR u_src = w ^ (e&31),
  // e&31 = ((c&1)<<4) | (tid>>5).
  {
    const int eh = tid >> 5;                                        // 0..15
#pragma unroll
    for (int c = 0; c < 4; ++c) {
      int e = c * 16 + eh;
      unsigned xv = (unsigned)((((c & 1) << 4) | eh));
      unsigned wsw = (((unsigned)(tid & 31)) ^ xv) << 4;
      unsigned so = ((unsigned)src[row0 + e] << 9) + wsw;
      unsigned do_ = ((unsigned)dst[row0 + e] << 9) + wsw;
      async_gather16(nodeB + so, smem + c * 8192 + wid * 1024);
      async_gather16(nodeB + do_, smem + 32768 + c * 8192 + wid * 1024);
    }
  }
  __syncthreads();  // staging barrier

#pragma unroll 2
  for (int step = 0; step < 8; ++step) {
    // B(t) loads — compiler emits fine-grained vmcnt
    V16 bf[4][2][2];  // [s][slice][nt2]
#pragma unroll
    for (int s = 0; s < 4; ++s)
#pragma unroll
      for (int sl = 0; sl < 2; ++sl)
#pragma unroll
        for (int nt2 = 0; nt2 < 2; ++nt2)
          bf[s][sl][nt2].u = *(const uint4*)(
              w1s + (bQ + (unsigned)(s * 32768 + sl * 16384 + nt2 * 512)));
    // A fragments from LDS (read-only, no sync needed)
    V16 hi[2][2], hj[2][2];  // [mt2][slice]
#pragma unroll
    for (int mt2 = 0; mt2 < 2; ++mt2)
#pragma unroll
      for (int sl = 0; sl < 2; ++sl) {
        unsigned u = (unsigned)(step * 4 + sl * 2 + khalf);
        unsigned ao = (unsigned)(mt2 * 16384) + aBase + ((u ^ aXor) << 4);
        hi[mt2][sl].u = *(const uint4*)(smem + ao);
        hj[mt2][sl].u = *(const uint4*)(smem + 32768 + ao);
      }
    // MFMA s=0 (hi), s=1 (hj)
#pragma unroll
    for (int mt2 = 0; mt2 < 2; ++mt2)
#pragma unroll
      for (int sl = 0; sl < 2; ++sl)
#pragma unroll
        for (int nt2 = 0; nt2 < 2; ++nt2)
          acc[mt2][nt2] = __builtin_amdgcn_mfma_f32_32x32x16_f16(
              hi[mt2][sl].h, bf[0][sl][nt2].h, acc[mt2][nt2], 0, 0, 0);
#pragma unroll
    for (int mt2 = 0; mt2 < 2; ++mt2)
#pragma unroll
      for (int sl = 0; sl < 2; ++sl)
#pragma unroll
        for (int nt2 = 0; nt2 < 2; ++nt2)
          acc[mt2][nt2] = __builtin_amdgcn_mfma_f32_32x32x16_f16(
              hj[mt2][sl].h, bf[1][sl][nt2].h, acc[mt2][nt2], 0, 0, 0);
    // build a2=|hi-hj|, a3=hi*hj with packed fp16 (3 VALU/word), MFMA s=2,3
#pragma unroll
    for (int mt2 = 0; mt2 < 2; ++mt2)
#pragma unroll
      for (int sl = 0; sl < 2; ++sl) {
        const unsigned hw[4] = {hi[mt2][sl].u.x, hi[mt2][sl].u.y, hi[mt2][sl].u.z, hi[mt2][sl].u.w};
        const unsigned jw[4] = {hj[mt2][sl].u.x, hj[mt2][sl].u.y, hj[mt2][sl].u.z, hj[mt2][sl].u.w};
        unsigned d[4], pr[4];
#pragma unroll
        for (int w = 0; w < 4; ++w) {
          U32 hx, jx, dd, pp;
          hx.u = hw[w];
          jx.u = jw[w];
          dd.p = hx.p - jx.p;            // v_pk_add_f16 (neg mod)
          d[w] = dd.u & 0x7fff7fffu;     // abs: clear sign bits (exact)
          pp.p = hx.p * jx.p;            // v_pk_mul_f16
          pr[w] = pp.u;
        }
        V16 a2, a3;
        a2.u = make_uint4(d[0], d[1], d[2], d[3]);
        a3.u = make_uint4(pr[0], pr[1], pr[2], pr[3]);
#pragma unroll
        for (int nt2 = 0; nt2 < 2; ++nt2)
          acc[mt2][nt2] = __builtin_amdgcn_mfma_f32_32x32x16_f16(
              a2.h, bf[2][sl][nt2].h, acc[mt2][nt2], 0, 0, 0);
#pragma unroll
        for (int nt2 = 0; nt2 < 2; ++nt2)
          acc[mt2][nt2] = __builtin_amdgcn_mfma_f32_32x32x16_f16(
              a3.h, bf[3][sl][nt2].h, acc[mt2][nt2], 0, 0, 0);
      }
    w1s += 131072;
  }

  // ---- epilogue: bias + ReLU + W2, 32-lane-half shuffle reduce, LDS cross-wave
  //      reduction (smem reused) + ONE plain store per out element ----
  float* red = (float*)smem;   // [8 waves][64 edges][2] f32 = 4 KB
  __syncthreads();             // all waves done reading A tiles from LDS
  float b1v[2], w20[2], w21[2];
#pragma unroll
  for (int nt2 = 0; nt2 < 2; ++nt2) {
    int gc = n0 + nt2 * 32 + l32;
    b1v[nt2] = b1[gc];
    w20[nt2] = w2[gc * 2 + 0];
    w21[nt2] = w2[gc * 2 + 1];
  }
#pragma unroll
  for (int mt2 = 0; mt2 < 2; ++mt2) {
#pragma unroll
    for (int r = 0; r < 16; ++r) {
      float pc0 = 0.f, pc1 = 0.f;
#pragma unroll
      for (int nt2 = 0; nt2 < 2; ++nt2) {
        float v = fmaxf(acc[mt2][nt2][r] + b1v[nt2], 0.f);
        pc0 = fmaf(v, w20[nt2], pc0);
        pc1 = fmaf(v, w21[nt2], pc1);
      }
      // reduce over the 32-lane half (cols); halves hold different rows
#pragma unroll
      for (int off = 1; off < 32; off <<= 1) {
        pc0 += __shfl_xor(pc0, off);
        pc1 += __shfl_xor(pc1, off);
      }
      // C/D: row = (r&3) + 8*(r>>2) + 4*khalf
      int el = mt2 * 32 + (r & 3) + 8 * (r >> 2) + 4 * khalf;
      if (l32 == 0) red[wid * 128 + el * 2 + 0] = pc0;
      if (l32 == 1) red[wid * 128 + el * 2 + 1] = pc1;
    }
  }
  __syncthreads();
  if (tid < 128) {
    // tid = el*2 + c
    float s = b2[tid & 1];
#pragma unroll
    for (int w = 0; w < 8; ++w) s += red[w * 128 + tid];
    out[(size_t)row0 * 2 + tid] = s;
  }
}

extern "C" void kernel_launch(void* const* d_in, const int* in_sizes, int n_in,
                              void* d_out, int out_size, void* d_ws, size_t ws_size,
                              hipStream_t stream) {
  const float* node = (const float*)d_in[0];
  const int* src = (const int*)d_in[1];
  const int* dst = (const int*)d_in[2];
  const float* W1 = (const float*)d_in[3];
  const float* b1 = (const float*)d_in[4];
  const float* W2 = (const float*)d_in[5];
  const float* b2 = (const float*)d_in[6];
  float* out = (float*)d_out;

  unsigned short* nodeb = (unsigned short*)d_ws;                      // 25,600,000 B
  unsigned short* w1pp2 = (unsigned short*)((char*)d_ws + 25600000);  // 1,048,576 B

  prep_all_kernel<<<6506, 256, 0, stream>>>(node, W1, nodeb, w1pp2);
  edge_mlp_kernel<<<4096, 512, 0, stream>>>(nodeb, w1pp2, src, dst, b1, W2, b2, out);
}